// Round 12
// baseline (2765.003 us; speedup 1.0000x reference)
//
#include <hip/hip_runtime.h>
#include <cstdint>
#include <cstddef>

// ---------------- problem constants ----------------
static constexpr int TSEQ = 2048;   // T
static constexpr int PSEQ = 256;    // P
static constexpr int DIN  = 300;
static constexpr int NH1  = 600;
static constexpr int NH2  = 2048;

// ---------------- ws layout (bytes) ----------------
static constexpr size_t OFF_X1   = 0;                                   // [2048][2400] f32
static constexpr size_t SZ_X1    = (size_t)TSEQ * 4 * NH1 * 4;
// stage-1 h exchange: [2 parity][256 chains][150 u64] of 4x bf16 (untagged)
static constexpr size_t OFF_HBF  = OFF_X1 + SZ_X1;
static constexpr size_t SZ_HBF   = 2ull * PSEQ * 150 * 8;
static constexpr size_t OFF_EMB  = OFF_HBF + SZ_HBF;                    // [256][600] f32
static constexpr size_t SZ_EMB   = (size_t)PSEQ * NH1 * 4;
static constexpr size_t OFF_EMB2 = OFF_EMB + SZ_EMB;                    // [256][600] f32
static constexpr size_t SZ_EMB2  = (size_t)PSEQ * NH1 * 4;
static constexpr size_t OFF_X2   = OFF_EMB2 + SZ_EMB2;                  // [256][8192] f32
static constexpr size_t SZ_X2    = (size_t)PSEQ * 4 * NH2 * 4;
static constexpr size_t OFF_PH   = OFF_X2 + SZ_X2;                      // [256][2048] f32
static constexpr size_t SZ_PH    = (size_t)PSEQ * NH2 * 4;
static constexpr size_t OFF_S    = OFF_PH + SZ_PH;                      // [256][2048] f32
static constexpr size_t SZ_S     = (size_t)PSEQ * NH2 * 4;
// stage-2 h exchange: [2 parity][2048] f32 (untagged)
static constexpr size_t OFF_H2   = OFF_S + SZ_S;
static constexpr size_t SZ_H2    = 2ull * NH2 * 4;
static constexpr size_t OFF_SSUM = OFF_H2 + SZ_H2;                      // 2048 f32
static constexpr size_t OFF_TMP  = OFF_SSUM + 8192;                     // 2048 f32
static constexpr size_t OFF_META = OFF_TMP + 8192;                      // ints: st[256] L[256] ord[256] Ls[256] lmax
static constexpr size_t OFF_SYNC = OFF_META + 8192;                     // barrier counters (2 regions)
static constexpr size_t SZ_SYNC  = 16384;

// k_s1 dynamic LDS: W 32x600 bf16 + h 64x600 bf16 + g 32x68 f32 + c 256x8 f32 + meta 3x256 int
static constexpr int S1_LDS = (32*600 + 64*600) * 2 + 32*68*4 + 256*8*4 + 3*256*4;   // 135168

#define DEVI __device__ __forceinline__

typedef __attribute__((ext_vector_type(8))) short short8v;   // 8 bf16 (4 VGPRs)
typedef __attribute__((ext_vector_type(4))) float f32x4;     // MFMA acc

DEVI float sigm(float x) {
    x = fminf(30.f, fmaxf(-30.f, x));
    return 1.f / (1.f + __expf(-x));
}
DEVI float tanh_f(float x) {
    x = fminf(15.f, fmaxf(-15.f, x));
    float t = __expf(2.f * x);
    return (t - 1.f) / (t + 1.f);
}
DEVI uint16_t f2bf(float f) {  // RNE fp32->bf16
    uint32_t u = __float_as_uint(f);
    return (uint16_t)((u + 0x7fffu + ((u >> 16) & 1u)) >> 16);
}
DEVI float bflo(unsigned int u) { return __uint_as_float(u << 16); }
DEVI float bfhi(unsigned int u) { return __uint_as_float(u & 0xffff0000u); }

DEVI int ld_agent(const int* p) {
    return __hip_atomic_load(p, __ATOMIC_RELAXED, __HIP_MEMORY_SCOPE_AGENT);
}
DEVI uint64_t ldu64_agent(const uint64_t* p) {
    return __hip_atomic_load(p, __ATOMIC_RELAXED, __HIP_MEMORY_SCOPE_AGENT);
}
DEVI void stu_agent(unsigned int* p, unsigned int v) {
    __hip_atomic_store(p, v, __ATOMIC_RELAXED, __HIP_MEMORY_SCOPE_AGENT);
}
DEVI void stf_agent(float* p, float v) {
    __hip_atomic_store(p, v, __ATOMIC_RELAXED, __HIP_MEMORY_SCOPE_AGENT);
}

// ---- fence-free barrier v3 (r7-proven): bucket arrive -> root -> per-bucket go flags.
// Low poll concurrency: <=pb spinners per go line. area ints:
// arrive[b] @ b*32 ; root @ 600 ; go[b] @ 1024 + b*32.
DEVI void barrier3(int* area, int wgid, int nb, int pb, int phase) {
    __syncthreads();   // all waves' outstanding global (sc) stores retired
    if (threadIdx.x == 0) {
        const int b = wgid % nb;
        int old = __hip_atomic_fetch_add(&area[b * 32], 1,
                                         __ATOMIC_RELAXED, __HIP_MEMORY_SCOPE_AGENT);
        if ((old % pb) == pb - 1) {
            int old2 = __hip_atomic_fetch_add(&area[600], 1,
                                              __ATOMIC_RELAXED, __HIP_MEMORY_SCOPE_AGENT);
            if ((old2 % nb) == nb - 1) {           // last arriver overall -> releaser
                for (int i = 0; i < nb; ++i)
                    stu_agent((unsigned int*)&area[1024 + i * 32], (unsigned int)(phase + 1));
            }
        }
        while (ld_agent(&area[1024 + b * 32]) < phase + 1)
            __builtin_amdgcn_s_sleep(1);
    }
    __syncthreads();
}

// ---- distributed min-poll barrier (good at <=75 wgs; regresses at 256 — r10) ----
template <int NB, int PB>
DEVI void barrier4(int* area, int wgid, int phase) {
    __syncthreads();
    if (threadIdx.x == 0) {
        __hip_atomic_fetch_add(&area[(wgid % NB) * 32], 1,
                               __ATOMIC_RELAXED, __HIP_MEMORY_SCOPE_AGENT);
        const int tgt = PB * (phase + 1);
        for (;;) {
            int mn = 0x7fffffff;
#pragma unroll
            for (int i = 0; i < NB; ++i) {
                int v = ld_agent(&area[i * 32]);
                mn = mn < v ? mn : v;
            }
            if (mn >= tgt) break;
            __builtin_amdgcn_s_sleep(1);
        }
    }
    __syncthreads();
}

// ---------------- generic fp32 GEMM: out[t][r] = act(X[t]·W[r] + bA[r] (+ bB[r])) ----------------
template <int TBLK>
__global__ void __launch_bounds__(256) gemm_rows(
    const float* __restrict__ X, int T, int K,
    const float* __restrict__ W, int R,
    const float* __restrict__ bA, const float* __restrict__ bB,
    float* __restrict__ out, int act)
{
    __shared__ float xt[TBLK][448];
    const int r  = blockIdx.x * 256 + threadIdx.x;
    const int t0 = blockIdx.y * TBLK;
    float acc[TBLK];
#pragma unroll
    for (int i = 0; i < TBLK; ++i) acc[i] = 0.f;

    for (int kc0 = 0; kc0 < K; kc0 += 448) {
        const int kc  = (K - kc0 < 448) ? (K - kc0) : 448;
        const int kc4 = kc >> 2;
        __syncthreads();
        for (int idx = threadIdx.x; idx < TBLK * kc4; idx += 256) {
            int tt = idx / kc4, kk = idx - tt * kc4;
            float4 v = make_float4(0.f, 0.f, 0.f, 0.f);
            if (t0 + tt < T)
                v = *(const float4*)(X + (size_t)(t0 + tt) * K + kc0 + kk * 4);
            *(float4*)(&xt[tt][kk * 4]) = v;
        }
        __syncthreads();
        if (r < R) {
            const float4* wr = (const float4*)(W + (size_t)r * K + kc0);
            for (int k4 = 0; k4 < kc4; ++k4) {
                float4 w4 = wr[k4];
#pragma unroll
                for (int tt = 0; tt < TBLK; ++tt) {
                    float4 x4 = *(const float4*)(&xt[tt][k4 * 4]);
                    acc[tt] = fmaf(w4.x, x4.x, acc[tt]);
                    acc[tt] = fmaf(w4.y, x4.y, acc[tt]);
                    acc[tt] = fmaf(w4.z, x4.z, acc[tt]);
                    acc[tt] = fmaf(w4.w, x4.w, acc[tt]);
                }
            }
        }
    }
    if (r < R) {
        float bb = bA[r] + (bB ? bB[r] : 0.f);
#pragma unroll
        for (int tt = 0; tt < TBLK; ++tt) {
            if (t0 + tt < T) {
                float v = acc[tt] + bb;
                if (act) v = tanh_f(v);
                out[(size_t)(t0 + tt) * R + r] = v;
            }
        }
    }
}

// ---------------- segment starts + length-sort (1 block, 256 threads) ----------------
__global__ void __launch_bounds__(256) k_start(
    const float* __restrict__ action, const int* __restrict__ apos, int* __restrict__ meta)
{
    __shared__ int Lsh[256];
    const int p = threadIdx.x;
    const int pos = apos[p];
    int u = pos;
    while (u > 0 && action[u - 1] == 0.0f) --u;
    const int L = pos - u + 1;
    meta[p] = u;
    meta[256 + p] = L;
    Lsh[p] = L;
    __syncthreads();
    int rank = 0;
    for (int q = 0; q < 256; ++q) {
        int Lq = Lsh[q];
        if (Lq > L || (Lq == L && q < p)) ++rank;
    }
    meta[512 + rank] = p;
    meta[768 + rank] = L;
    if (rank == 0) meta[1024] = L;
}

// ---------------- stage-1 LSTM via MFMA: 75 wgs x 8 units (r10-proven form) ----------------
// In-order group sweep (all wgs read the SAME Hbuf lines together — coherence-point
// broadcast is cheap; staggering regressed in r11). Batched register staging, 1 RT.
__global__ void __launch_bounds__(512) k_s1(
    const float* __restrict__ X1, const float* __restrict__ Whh1,
    const int* __restrict__ meta,
    uint64_t* __restrict__ Hbuf, float* __restrict__ EMB, int* __restrict__ sync)
{
    extern __shared__ char smem[];
    unsigned short* wl = (unsigned short*)smem;            // [32][600] bf16
    unsigned short* hl = wl + 32 * 600;                    // [64][600] bf16
    float* glds = (float*)(hl + 64 * 600);                 // [32][68] gates
    float* clds = glds + 32 * 68;                          // [256][8] c-state
    int* ordC  = (int*)(clds + 256 * 8);
    int* ordST = ordC + 256;
    int* ordL  = ordST + 256;

    const int wg  = blockIdx.x;        // 0..74, owns units u0..u0+7
    const int u0  = wg * 8;
    const int tid = threadIdx.x;
    const int lane = tid & 63;
    const int w  = tid >> 6;
    const int ct = w & 3, rt = w >> 2;

    for (int idx = tid; idx < 32 * 150; idx += 512) {
        int rr = idx / 150, j = idx - rr * 150;
        int gamma = rr >> 3, u = rr & 7;
        float4 v = *(const float4*)(Whh1 + (size_t)(gamma * 600 + u0 + u) * 600 + j * 4);
        ushort4 pk = make_ushort4(f2bf(v.x), f2bf(v.y), f2bf(v.z), f2bf(v.w));
        *(ushort4*)(wl + rr * 600 + j * 4) = pk;
    }
    if (tid < 256) {
        int p = meta[512 + tid];
        ordC[tid]  = p;
        ordST[tid] = meta[p];
        ordL[tid]  = meta[256 + p];
    }
    for (int idx = tid; idx < 2048; idx += 512) clds[idx] = 0.f;
    __syncthreads();

    const int lmax = ordL[0];
    int A = 256;

    for (int k = 0; k < lmax; ++k) {
        while (A > 0 && ordL[A - 1] <= k) --A;
        const uint64_t* Hr = Hbuf + (size_t)(k & 1) * (PSEQ * 150);
        uint64_t*       Hw = Hbuf + (size_t)((k + 1) & 1) * (PSEQ * 150);
        const int ng = (A + 63) >> 6;

        for (int g = 0; g < ng; ++g) {
            const int sc  = (A - g * 64 < 64) ? (A - g * 64) : 64;
            const int nst = (sc + 15) & ~15;
            __syncthreads();   // previous group's MFMA reads of hl are done

            // stage h(k): ALL of this thread's u64 loads in flight (1 RT), then LDS writes
            {
                uint64_t vv[19];
                const int tot = sc * 150;
#pragma unroll
                for (int q = 0; q < 19; ++q) {
                    const int idx = tid + q * 512;
                    if (idx < tot) {
                        const int ci = idx / 150, j = idx - ci * 150;
                        const int ch = ordC[g * 64 + ci];
                        vv[q] = ldu64_agent(Hr + (size_t)ch * 150 + j);
                    }
                }
#pragma unroll
                for (int q = 0; q < 19; ++q) {
                    const int idx = tid + q * 512;
                    if (idx < tot) {
                        const int ci = idx / 150, j = idx - ci * 150;
                        *(uint2*)((unsigned int*)(hl + (size_t)ci * 600) + j * 2) =
                            make_uint2((unsigned int)vv[q], (unsigned int)(vv[q] >> 32));
                    }
                }
            }
            // zero-fill MFMA padding rows [sc, nst)
            for (int idx = tid; idx < (nst - sc) * 300; idx += 512) {
                int ci = sc + idx / 300, j2 = idx - (idx / 300) * 300;
                *((unsigned int*)(hl + (size_t)ci * 600) + j2) = 0u;
            }
            __syncthreads();

            // epilogue-role prefetch: X1 gate values + meta (independent of h)
            const int s_loc = tid >> 3, eu = tid & 7;
            const bool ep = (s_loc < sc);
            int ch = 0, st = 0, L = 0;
            float xv0 = 0, xv1 = 0, xv2 = 0, xv3 = 0;
            if (ep) {
                ch = ordC[g * 64 + s_loc];
                st = ordST[g * 64 + s_loc];
                L  = ordL[g * 64 + s_loc];
                const float* xr = X1 + (size_t)(st + k) * 2400 + u0 + eu;
                xv0 = xr[0]; xv1 = xr[600]; xv2 = xr[1200]; xv3 = xr[1800];
            }

            // MFMA: D[chain][row] += h · W^T
            if (ct * 16 < sc) {
                f32x4 acc = {0.f, 0.f, 0.f, 0.f};
                const int kg = lane >> 4;
                const short* ha = (const short*)hl + (ct * 16 + (lane & 15)) * 600;
                const short* wb = (const short*)wl + (rt * 16 + (lane & 15)) * 600;
#pragma unroll
                for (int kt = 0; kt < 19; ++kt) {
                    int k0 = kt * 32 + kg * 8;
                    short8v af = {0, 0, 0, 0, 0, 0, 0, 0};
                    short8v bf = {0, 0, 0, 0, 0, 0, 0, 0};
                    if (k0 < 600) {
                        af = *(const short8v*)(ha + k0);
                        bf = *(const short8v*)(wb + k0);
                    }
                    acc = __builtin_amdgcn_mfma_f32_16x16x32_bf16(af, bf, acc, 0, 0, 0);
                }
                const int brow = rt * 16 + (lane & 15);
                const int ch0  = ct * 16 + ((lane >> 4) << 2);
                *(f32x4*)(glds + brow * 68 + ch0) = acc;
            }
            __syncthreads();

            // gate epilogue: compute unconditionally, guard stores with ep
            {
                float gi = glds[(0 * 8 + eu) * 68 + s_loc] + xv0;
                float gf = glds[(1 * 8 + eu) * 68 + s_loc] + xv1;
                float gg = glds[(2 * 8 + eu) * 68 + s_loc] + xv2;
                float go = glds[(3 * 8 + eu) * 68 + s_loc] + xv3;
                float co = clds[ch * 8 + eu];
                float cn = sigm(gf) * co + sigm(gi) * tanh_f(gg);
                float hn = sigm(go) * tanh_f(cn);
                if (ep) clds[ch * 8 + eu] = cn;
                unsigned int pk = (unsigned int)f2bf(hn);
                unsigned int hi = __shfl_down(pk, 1, 64);
                if (ep && (eu & 1) == 0)
                    stu_agent((unsigned int*)Hw + (size_t)ch * 300 + ((u0 + eu) >> 1),
                              pk | (hi << 16));
                if (ep && k == L - 1)
                    EMB[(size_t)ch * 600 + u0 + eu] = hn;
            }
        }
        if (k < lmax - 1) barrier4<15, 5>(sync, wg, k);   // 75 = 15 buckets x 5
    }
}

// ---------------- stage-2 LSTM: 128 wgs x 16 units; 1024 thr; wave w owns unit w ----------------
// Halved barrier population vs r7 (256->128). Per wave: 4 gate rows bf16-packed in
// 64 VGPRs (fits the 128-VGPR cap of 16-wave blocks); unpack via <<16 / &0xffff0000.
__global__ void __launch_bounds__(1024) k_s2(
    const float* __restrict__ X2, const float* __restrict__ Whh2,
    float* __restrict__ h2, float* __restrict__ PH, int* __restrict__ sync)
{
    __shared__ float hl[NH2];
    const int wg   = blockIdx.x;        // 0..127
    const int tid  = threadIdx.x;
    const int lane = tid & 63;
    const int w    = tid >> 6;          // wave = unit 0..15
    const int uu   = wg * 16 + w;
    int* syncg = sync + 2048;           // s2 region

    // pack 4 gate rows bf16 into 64 VGPRs: wp[g][j*2+h] packs k = j*256 + lane*4 + {2h, 2h+1}
    unsigned int wp[4][16];
#pragma unroll
    for (int g = 0; g < 4; ++g) {
        const float* rp = Whh2 + ((size_t)(g * NH2 + uu)) * NH2 + lane * 4;
#pragma unroll
        for (int j = 0; j < 8; ++j) {
            float4 a = *(const float4*)(rp + j * 256);
            wp[g][j * 2 + 0] = (unsigned int)f2bf(a.x) | ((unsigned int)f2bf(a.y) << 16);
            wp[g][j * 2 + 1] = (unsigned int)f2bf(a.z) | ((unsigned int)f2bf(a.w) << 16);
        }
    }
    *(float2*)(hl + tid * 2) = make_float2(0.f, 0.f);   // h(0) = 0
    float creg = 0.f;
    __syncthreads();

    for (int t = 0; t < PSEQ; ++t) {
        // prefetch x gate values (lane0 of each wave), independent of h
        float x0 = 0, x1 = 0, x2 = 0, x3 = 0;
        if (lane == 0) {
            const float* xr = X2 + (size_t)t * (4 * NH2) + uu;
            x0 = xr[0]; x1 = xr[NH2]; x2 = xr[2 * NH2]; x3 = xr[3 * NH2];
        }
        float a0 = 0, a1 = 0, a2 = 0, a3 = 0;
#pragma unroll
        for (int j = 0; j < 8; ++j) {
            float4 hv = *(const float4*)(hl + j * 256 + lane * 4);
            unsigned int p00 = wp[0][j*2], p01 = wp[0][j*2+1];
            unsigned int p10 = wp[1][j*2], p11 = wp[1][j*2+1];
            unsigned int p20 = wp[2][j*2], p21 = wp[2][j*2+1];
            unsigned int p30 = wp[3][j*2], p31 = wp[3][j*2+1];
            a0 = fmaf(bflo(p00), hv.x, a0); a0 = fmaf(bfhi(p00), hv.y, a0);
            a0 = fmaf(bflo(p01), hv.z, a0); a0 = fmaf(bfhi(p01), hv.w, a0);
            a1 = fmaf(bflo(p10), hv.x, a1); a1 = fmaf(bfhi(p10), hv.y, a1);
            a1 = fmaf(bflo(p11), hv.z, a1); a1 = fmaf(bfhi(p11), hv.w, a1);
            a2 = fmaf(bflo(p20), hv.x, a2); a2 = fmaf(bfhi(p20), hv.y, a2);
            a2 = fmaf(bflo(p21), hv.z, a2); a2 = fmaf(bfhi(p21), hv.w, a2);
            a3 = fmaf(bflo(p30), hv.x, a3); a3 = fmaf(bfhi(p30), hv.y, a3);
            a3 = fmaf(bflo(p31), hv.z, a3); a3 = fmaf(bfhi(p31), hv.w, a3);
        }
#pragma unroll
        for (int m = 32; m > 0; m >>= 1) {
            a0 += __shfl_xor(a0, m, 64); a1 += __shfl_xor(a1, m, 64);
            a2 += __shfl_xor(a2, m, 64); a3 += __shfl_xor(a3, m, 64);
        }
        if (lane == 0) {
            float gi = a0 + x0, gf = a1 + x1, gg = a2 + x2, go = a3 + x3;
            float cn = sigm(gf) * creg + sigm(gi) * tanh_f(gg);
            float hn = sigm(go) * tanh_f(cn);
            creg = cn;
            stf_agent(h2 + (size_t)((t + 1) & 1) * NH2 + uu, hn);
            PH[(size_t)t * NH2 + uu] = hn;
        }
        if (t < PSEQ - 1) {
            barrier3(syncg, wg, 16, 8, t);   // 128 = 16 buckets x 8
            // stage h(t+1): 1 u64 agent load per thread -> float2 LDS write
            uint64_t v = ldu64_agent((const uint64_t*)(h2 + (size_t)((t + 1) & 1) * NH2) + tid);
            *(float2*)(hl + tid * 2) =
                make_float2(__uint_as_float((unsigned int)v),
                            __uint_as_float((unsigned int)(v >> 32)));
            __syncthreads();
        }
    }
}

// ---------------- column sum of S -> SSUM ----------------
__global__ void __launch_bounds__(256) k_colsum(const float* __restrict__ S, float* __restrict__ out)
{
    const int j = blockIdx.x * 256 + threadIdx.x;
    float a = 0.f;
    for (int t = 0; t < PSEQ; ++t) a += S[(size_t)t * NH2 + j];
    out[j] = a;
}

// ---------------- matvec: vout[r] = W[r]·vin + bscale*b[r] ----------------
__global__ void __launch_bounds__(256) k_mv(
    const float* __restrict__ W, const float* __restrict__ b, float bscale,
    const float* __restrict__ vin, float* __restrict__ vout)
{
    __shared__ float v[NH2];
    for (int i = threadIdx.x; i < NH2; i += 256) v[i] = vin[i];
    __syncthreads();
    const int r = blockIdx.x * 256 + threadIdx.x;
    const float4* wr = (const float4*)(W + (size_t)r * NH2);
    float a0 = 0, a1 = 0, a2 = 0, a3 = 0;
    for (int k4 = 0; k4 < NH2 / 4; ++k4) {
        float4 w4 = wr[k4];
        float4 x4 = *(const float4*)(&v[k4 * 4]);
        a0 = fmaf(w4.x, x4.x, a0); a1 = fmaf(w4.y, x4.y, a1);
        a2 = fmaf(w4.z, x4.z, a2); a3 = fmaf(w4.w, x4.w, a3);
    }
    vout[r] = (a0 + a1) + (a2 + a3) + bscale * b[r];
}

extern "C" void kernel_launch(void* const* d_in, const int* in_sizes, int n_in,
                              void* d_out, int out_size, void* d_ws, size_t ws_size,
                              hipStream_t stream)
{
    const float* sent   = (const float*)d_in[0];
    const float* action = (const float*)d_in[1];
    const int*   apos   = (const int*)  d_in[2];
    const float* Wih1   = (const float*)d_in[3];
    const float* Whh1   = (const float*)d_in[4];
    const float* bih1   = (const float*)d_in[5];
    const float* bhh1   = (const float*)d_in[6];
    const float* W1     = (const float*)d_in[7];
    const float* b1     = (const float*)d_in[8];
    const float* Wih2   = (const float*)d_in[9];
    const float* Whh2   = (const float*)d_in[10];
    const float* bih2   = (const float*)d_in[11];
    const float* bhh2   = (const float*)d_in[12];
    const float* W2     = (const float*)d_in[13];
    const float* b2     = (const float*)d_in[14];
    const float* ipw    = (const float*)d_in[15];
    const float* ipb    = (const float*)d_in[16];
    const float* opw    = (const float*)d_in[17];
    const float* opb    = (const float*)d_in[18];

    char* ws = (char*)d_ws;
    float*     X1   = (float*)(ws + OFF_X1);
    uint64_t*  HBUF = (uint64_t*)(ws + OFF_HBF);
    float*     EMB  = (float*)(ws + OFF_EMB);
    float*     EMB2 = (float*)(ws + OFF_EMB2);
    float*     X2   = (float*)(ws + OFF_X2);
    float*     PH   = (float*)(ws + OFF_PH);
    float*     S    = (float*)(ws + OFF_S);
    float*     H2   = (float*)(ws + OFF_H2);
    float*     SSUM = (float*)(ws + OFF_SSUM);
    float*     TMP  = (float*)(ws + OFF_TMP);
    int*       META = (int*)  (ws + OFF_META);
    int*       SYNC = (int*)  (ws + OFF_SYNC);

    // re-zero h(0) buffers + barrier counters every call (graph replays)
    hipMemsetAsync(ws + OFF_HBF, 0, SZ_HBF, stream);
    hipMemsetAsync(ws + OFF_H2, 0, SZ_H2, stream);
    hipMemsetAsync(ws + OFF_SYNC, 0, SZ_SYNC, stream);

    hipFuncSetAttribute((const void*)k_s1, hipFuncAttributeMaxDynamicSharedMemorySize, S1_LDS);

    // X1 = sent @ Wih1.T + bih1 + bhh1   (2048 x 2400, K=300)
    gemm_rows<32><<<dim3(10, 64), 256, 0, stream>>>(sent, TSEQ, DIN, Wih1, 4 * NH1, bih1, bhh1, X1, 0);
    // segment starts / lengths / sort
    k_start<<<1, 256, 0, stream>>>(action, apos, META);
    // stage-1 chains (MFMA, r10 form) -> EMB
    k_s1<<<75, 512, S1_LDS, stream>>>(X1, Whh1, META, HBUF, EMB, SYNC);
    // EMB2 = tanh(EMB @ W1.T + b1)       (256 x 600, K=600)
    gemm_rows<32><<<dim3(3, 8), 256, 0, stream>>>(EMB, PSEQ, NH1, W1, NH1, b1, nullptr, EMB2, 1);
    // X2 = EMB2 @ Wih2.T + bih2 + bhh2   (256 x 8192, K=600)
    gemm_rows<32><<<dim3(32, 8), 256, 0, stream>>>(EMB2, PSEQ, NH1, Wih2, 4 * NH2, bih2, bhh2, X2, 0);
    // stage-2 LSTM (128 wgs x 16 units, barrier3) -> PH (256 x 2048)
    k_s2<<<128, 1024, 0, stream>>>(X2, Whh2, H2, PH, SYNC);
    // S = tanh(PH @ W2.T + b2)           (256 x 2048, K=2048)
    gemm_rows<32><<<dim3(8, 8), 256, 0, stream>>>(PH, PSEQ, NH2, W2, NH2, b2, nullptr, S, 1);
    // SSUM = column sums of S
    k_colsum<<<8, 256, 0, stream>>>(S, SSUM);
    // attention collapse: out = (SSUM @ Wv.T + 256*bv) @ Wo.T + 256*bo
    k_mv<<<8, 256, 0, stream>>>(ipw + (size_t)4096 * NH2, ipb + 4096, 256.f, SSUM, TMP);
    k_mv<<<8, 256, 0, stream>>>(opw, opb, 256.f, TMP, (float*)d_out);
}

// Round 13
// 1647.534 us; speedup vs baseline: 1.6783x; 1.6783x over previous
//
#include <hip/hip_runtime.h>
#include <cstdint>
#include <cstddef>

// ---------------- problem constants ----------------
static constexpr int TSEQ = 2048;   // T
static constexpr int PSEQ = 256;    // P
static constexpr int DIN  = 300;
static constexpr int NH1  = 600;
static constexpr int NH2  = 2048;

// ---------------- ws layout (bytes) ----------------
static constexpr size_t OFF_X1   = 0;                                   // [2048][2400] f32
static constexpr size_t SZ_X1    = (size_t)TSEQ * 4 * NH1 * 4;
// stage-1 h exchange: [2 parity][256 chains][150 u64] of 4x bf16 (untagged)
static constexpr size_t OFF_HBF  = OFF_X1 + SZ_X1;
static constexpr size_t SZ_HBF   = 2ull * PSEQ * 150 * 8;
static constexpr size_t OFF_EMB  = OFF_HBF + SZ_HBF;                    // [256][600] f32
static constexpr size_t SZ_EMB   = (size_t)PSEQ * NH1 * 4;
static constexpr size_t OFF_EMB2 = OFF_EMB + SZ_EMB;                    // [256][600] f32
static constexpr size_t SZ_EMB2  = (size_t)PSEQ * NH1 * 4;
static constexpr size_t OFF_X2   = OFF_EMB2 + SZ_EMB2;                  // [256][8192] f32
static constexpr size_t SZ_X2    = (size_t)PSEQ * 4 * NH2 * 4;
static constexpr size_t OFF_PH   = OFF_X2 + SZ_X2;                      // [256][2048] f32
static constexpr size_t SZ_PH    = (size_t)PSEQ * NH2 * 4;
static constexpr size_t OFF_S    = OFF_PH + SZ_PH;                      // [256][2048] f32
static constexpr size_t SZ_S     = (size_t)PSEQ * NH2 * 4;
// stage-2 h exchange: [2 parity][2048] f32 (untagged)
static constexpr size_t OFF_H2   = OFF_S + SZ_S;
static constexpr size_t SZ_H2    = 2ull * NH2 * 4;
static constexpr size_t OFF_SSUM = OFF_H2 + SZ_H2;                      // 2048 f32
static constexpr size_t OFF_TMP  = OFF_SSUM + 8192;                     // 2048 f32
static constexpr size_t OFF_META = OFF_TMP + 8192;                      // ints: st[256] L[256] ord[256] Ls[256] lmax
static constexpr size_t OFF_SYNC = OFF_META + 8192;                     // barrier counters (2 regions)
static constexpr size_t SZ_SYNC  = 16384;

// k_s1 dynamic LDS: W 32x600 bf16 + h 64x600 bf16 + g 32x68 f32 + c 256x8 f32 + meta 3x256 int
static constexpr int S1_LDS = (32*600 + 64*600) * 2 + 32*68*4 + 256*8*4 + 3*256*4;   // 135168
// gemm_mfma LDS: X [128][264] bf16 + W [128][264] bf16
static constexpr int GM_LDS = 2 * 128 * 264 * 2;                                     // 135168

#define DEVI __device__ __forceinline__

typedef __attribute__((ext_vector_type(8))) short short8v;   // 8 bf16 (4 VGPRs)
typedef __attribute__((ext_vector_type(4))) float f32x4;     // MFMA acc

DEVI float sigm(float x) {
    x = fminf(30.f, fmaxf(-30.f, x));
    return 1.f / (1.f + __expf(-x));
}
DEVI float tanh_f(float x) {
    x = fminf(15.f, fmaxf(-15.f, x));
    float t = __expf(2.f * x);
    return (t - 1.f) / (t + 1.f);
}
DEVI uint16_t f2bf(float f) {  // RNE fp32->bf16
    uint32_t u = __float_as_uint(f);
    return (uint16_t)((u + 0x7fffu + ((u >> 16) & 1u)) >> 16);
}

DEVI int ld_agent(const int* p) {
    return __hip_atomic_load(p, __ATOMIC_RELAXED, __HIP_MEMORY_SCOPE_AGENT);
}
DEVI uint64_t ldu64_agent(const uint64_t* p) {
    return __hip_atomic_load(p, __ATOMIC_RELAXED, __HIP_MEMORY_SCOPE_AGENT);
}
DEVI float ldf_agent(const float* p) {
    return __hip_atomic_load(p, __ATOMIC_RELAXED, __HIP_MEMORY_SCOPE_AGENT);
}
DEVI void stu_agent(unsigned int* p, unsigned int v) {
    __hip_atomic_store(p, v, __ATOMIC_RELAXED, __HIP_MEMORY_SCOPE_AGENT);
}
DEVI void stf_agent(float* p, float v) {
    __hip_atomic_store(p, v, __ATOMIC_RELAXED, __HIP_MEMORY_SCOPE_AGENT);
}

// ---- fence-free barrier v3 (r7-proven best at 256 wgs): arrive -> root -> go flags ----
DEVI void barrier3(int* area, int wgid, int nb, int pb, int phase) {
    __syncthreads();   // all waves' outstanding global (sc) stores retired
    if (threadIdx.x == 0) {
        const int b = wgid % nb;
        int old = __hip_atomic_fetch_add(&area[b * 32], 1,
                                         __ATOMIC_RELAXED, __HIP_MEMORY_SCOPE_AGENT);
        if ((old % pb) == pb - 1) {
            int old2 = __hip_atomic_fetch_add(&area[600], 1,
                                              __ATOMIC_RELAXED, __HIP_MEMORY_SCOPE_AGENT);
            if ((old2 % nb) == nb - 1) {           // last arriver overall -> releaser
                for (int i = 0; i < nb; ++i)
                    stu_agent((unsigned int*)&area[1024 + i * 32], (unsigned int)(phase + 1));
            }
        }
        while (ld_agent(&area[1024 + b * 32]) < phase + 1)
            __builtin_amdgcn_s_sleep(1);
    }
    __syncthreads();
}

// ---- distributed min-poll barrier (proven at 75 wgs; regresses at 256 — r10) ----
template <int NB, int PB>
DEVI void barrier4(int* area, int wgid, int phase) {
    __syncthreads();
    if (threadIdx.x == 0) {
        __hip_atomic_fetch_add(&area[(wgid % NB) * 32], 1,
                               __ATOMIC_RELAXED, __HIP_MEMORY_SCOPE_AGENT);
        const int tgt = PB * (phase + 1);
        for (;;) {
            int mn = 0x7fffffff;
#pragma unroll
            for (int i = 0; i < NB; ++i) {
                int v = ld_agent(&area[i * 32]);
                mn = mn < v ? mn : v;
            }
            if (mn >= tgt) break;
            __builtin_amdgcn_s_sleep(1);
        }
    }
    __syncthreads();
}

// ---------------- bf16 MFMA GEMM: out[t][r] = act(X[t]·W[r] + bA[r] (+ bB[r])) ----------------
// Tile 128T x 128R, K-chunks of 256 (zero-padded in LDS), 8 waves (2T x 4R),
// per wave 64Tx32R = 4x2 MFMA 16x16 tiles. Fragment mapping verified in k_s1.
// Requires: T multiple of 128 or of 64*? (here all T in {2048,256} are multiples of 128);
// R ragged ok (zero-filled rows, guarded stores); K-chunk sizes multiple of 4.
__global__ void __launch_bounds__(512) gemm_mfma(
    const float* __restrict__ X, int T, int K,
    const float* __restrict__ W, int R,
    const float* __restrict__ bA, const float* __restrict__ bB,
    float* __restrict__ out, int act)
{
    extern __shared__ char sm[];
    unsigned short* xl = (unsigned short*)sm;      // [128][264] bf16
    unsigned short* wl = xl + 128 * 264;           // [128][264] bf16
    const int tid  = threadIdx.x;
    const int lane = tid & 63;
    const int w    = tid >> 6;
    const int wt   = w & 1;        // T half (64 rows)
    const int wr   = w >> 1;       // R quarter (32 rows)
    const int t0   = blockIdx.x * 128;
    const int r0   = blockIdx.y * 128;

    f32x4 acc[4][2];
#pragma unroll
    for (int a = 0; a < 4; ++a)
#pragma unroll
        for (int b = 0; b < 2; ++b) acc[a][b] = f32x4{0.f, 0.f, 0.f, 0.f};

    for (int kc0 = 0; kc0 < K; kc0 += 256) {
        const int kc  = (K - kc0 < 256) ? (K - kc0) : 256;
        const int ktc = (kc + 31) >> 5;
        __syncthreads();
        // stage X and W tiles (f32 -> bf16), zero-fill k >= K and rows >= R
        for (int idx = tid; idx < 128 * 64; idx += 512) {
            const int row = idx >> 6, j4 = idx & 63;
            const int kk = kc0 + j4 * 4;
            float4 xv = make_float4(0.f, 0.f, 0.f, 0.f);
            float4 wv = make_float4(0.f, 0.f, 0.f, 0.f);
            if (kk < K) {   // K-chunks are multiples of 4 -> full float4 or nothing
                xv = *(const float4*)(X + (size_t)(t0 + row) * K + kk);
                if (r0 + row < R)
                    wv = *(const float4*)(W + (size_t)(r0 + row) * K + kk);
            }
            *(ushort4*)(xl + row * 264 + j4 * 4) =
                make_ushort4(f2bf(xv.x), f2bf(xv.y), f2bf(xv.z), f2bf(xv.w));
            *(ushort4*)(wl + row * 264 + j4 * 4) =
                make_ushort4(f2bf(wv.x), f2bf(wv.y), f2bf(wv.z), f2bf(wv.w));
        }
        __syncthreads();

        for (int kt = 0; kt < ktc; ++kt) {
            const int k0 = kt * 32 + (lane >> 4) * 8;
            short8v af[4], bf[2];
#pragma unroll
            for (int a = 0; a < 4; ++a)
                af[a] = *(const short8v*)((const short*)xl +
                        (wt * 64 + a * 16 + (lane & 15)) * 264 + k0);
#pragma unroll
            for (int b = 0; b < 2; ++b)
                bf[b] = *(const short8v*)((const short*)wl +
                        (wr * 32 + b * 16 + (lane & 15)) * 264 + k0);
#pragma unroll
            for (int a = 0; a < 4; ++a)
#pragma unroll
                for (int b = 0; b < 2; ++b)
                    acc[a][b] = __builtin_amdgcn_mfma_f32_16x16x32_bf16(
                        af[a], bf[b], acc[a][b], 0, 0, 0);
        }
    }

    // epilogue: D lane mapping — t = base + (lane>>4)*4 + i, r = base + (lane&15)
#pragma unroll
    for (int b = 0; b < 2; ++b) {
        const int r = r0 + wr * 32 + b * 16 + (lane & 15);
        if (r < R) {
            const float bb = bA[r] + (bB ? bB[r] : 0.f);
#pragma unroll
            for (int a = 0; a < 4; ++a) {
                const int t = t0 + wt * 64 + a * 16 + ((lane >> 4) << 2);
#pragma unroll
                for (int i = 0; i < 4; ++i) {
                    float v = acc[a][b][i] + bb;
                    if (act) v = tanh_f(v);
                    out[(size_t)(t + i) * R + r] = v;
                }
            }
        }
    }
}

// ---------------- segment starts + length-sort (1 block, 256 threads, LDS scan) ----------------
__global__ void __launch_bounds__(256) k_start(
    const float* __restrict__ action, const int* __restrict__ apos, int* __restrict__ meta)
{
    __shared__ float acts[TSEQ];
    __shared__ int Lsh[256];
    for (int i = threadIdx.x; i < TSEQ; i += 256) acts[i] = action[i];
    __syncthreads();
    const int p = threadIdx.x;
    const int pos = apos[p];
    int u = pos;
    while (u > 0 && acts[u - 1] == 0.0f) --u;
    const int L = pos - u + 1;
    meta[p] = u;
    meta[256 + p] = L;
    Lsh[p] = L;
    __syncthreads();
    int rank = 0;
    for (int q = 0; q < 256; ++q) {
        int Lq = Lsh[q];
        if (Lq > L || (Lq == L && q < p)) ++rank;
    }
    meta[512 + rank] = p;
    meta[768 + rank] = L;
    if (rank == 0) meta[1024] = L;
}

// ---------------- stage-1 LSTM via MFMA: 75 wgs x 8 units (r10-proven form) ----------------
__global__ void __launch_bounds__(512) k_s1(
    const float* __restrict__ X1, const float* __restrict__ Whh1,
    const int* __restrict__ meta,
    uint64_t* __restrict__ Hbuf, float* __restrict__ EMB, int* __restrict__ sync)
{
    extern __shared__ char smem[];
    unsigned short* wl = (unsigned short*)smem;            // [32][600] bf16
    unsigned short* hl = wl + 32 * 600;                    // [64][600] bf16
    float* glds = (float*)(hl + 64 * 600);                 // [32][68] gates
    float* clds = glds + 32 * 68;                          // [256][8] c-state
    int* ordC  = (int*)(clds + 256 * 8);
    int* ordST = ordC + 256;
    int* ordL  = ordST + 256;

    const int wg  = blockIdx.x;        // 0..74, owns units u0..u0+7
    const int u0  = wg * 8;
    const int tid = threadIdx.x;
    const int lane = tid & 63;
    const int w  = tid >> 6;
    const int ct = w & 3, rt = w >> 2;

    for (int idx = tid; idx < 32 * 150; idx += 512) {
        int rr = idx / 150, j = idx - rr * 150;
        int gamma = rr >> 3, u = rr & 7;
        float4 v = *(const float4*)(Whh1 + (size_t)(gamma * 600 + u0 + u) * 600 + j * 4);
        ushort4 pk = make_ushort4(f2bf(v.x), f2bf(v.y), f2bf(v.z), f2bf(v.w));
        *(ushort4*)(wl + rr * 600 + j * 4) = pk;
    }
    if (tid < 256) {
        int p = meta[512 + tid];
        ordC[tid]  = p;
        ordST[tid] = meta[p];
        ordL[tid]  = meta[256 + p];
    }
    for (int idx = tid; idx < 2048; idx += 512) clds[idx] = 0.f;
    __syncthreads();

    const int lmax = ordL[0];
    int A = 256;

    for (int k = 0; k < lmax; ++k) {
        while (A > 0 && ordL[A - 1] <= k) --A;
        const uint64_t* Hr = Hbuf + (size_t)(k & 1) * (PSEQ * 150);
        uint64_t*       Hw = Hbuf + (size_t)((k + 1) & 1) * (PSEQ * 150);
        const int ng = (A + 63) >> 6;

        for (int g = 0; g < ng; ++g) {
            const int sc  = (A - g * 64 < 64) ? (A - g * 64) : 64;
            const int nst = (sc + 15) & ~15;
            __syncthreads();   // previous group's MFMA reads of hl are done

            // stage h(k): ALL of this thread's u64 loads in flight (1 RT), then LDS writes
            {
                uint64_t vv[19];
                const int tot = sc * 150;
#pragma unroll
                for (int q = 0; q < 19; ++q) {
                    const int idx = tid + q * 512;
                    if (idx < tot) {
                        const int ci = idx / 150, j = idx - ci * 150;
                        const int ch = ordC[g * 64 + ci];
                        vv[q] = ldu64_agent(Hr + (size_t)ch * 150 + j);
                    }
                }
#pragma unroll
                for (int q = 0; q < 19; ++q) {
                    const int idx = tid + q * 512;
                    if (idx < tot) {
                        const int ci = idx / 150, j = idx - ci * 150;
                        *(uint2*)((unsigned int*)(hl + (size_t)ci * 600) + j * 2) =
                            make_uint2((unsigned int)vv[q], (unsigned int)(vv[q] >> 32));
                    }
                }
            }
            // zero-fill MFMA padding rows [sc, nst)
            for (int idx = tid; idx < (nst - sc) * 300; idx += 512) {
                int ci = sc + idx / 300, j2 = idx - (idx / 300) * 300;
                *((unsigned int*)(hl + (size_t)ci * 600) + j2) = 0u;
            }
            __syncthreads();

            // epilogue-role prefetch: X1 gate values + meta (independent of h)
            const int s_loc = tid >> 3, eu = tid & 7;
            const bool ep = (s_loc < sc);
            int ch = 0, st = 0, L = 0;
            float xv0 = 0, xv1 = 0, xv2 = 0, xv3 = 0;
            if (ep) {
                ch = ordC[g * 64 + s_loc];
                st = ordST[g * 64 + s_loc];
                L  = ordL[g * 64 + s_loc];
                const float* xr = X1 + (size_t)(st + k) * 2400 + u0 + eu;
                xv0 = xr[0]; xv1 = xr[600]; xv2 = xr[1200]; xv3 = xr[1800];
            }

            // MFMA: D[chain][row] += h · W^T
            if (ct * 16 < sc) {
                f32x4 acc = {0.f, 0.f, 0.f, 0.f};
                const int kg = lane >> 4;
                const short* ha = (const short*)hl + (ct * 16 + (lane & 15)) * 600;
                const short* wb = (const short*)wl + (rt * 16 + (lane & 15)) * 600;
#pragma unroll
                for (int kt = 0; kt < 19; ++kt) {
                    int k0 = kt * 32 + kg * 8;
                    short8v af = {0, 0, 0, 0, 0, 0, 0, 0};
                    short8v bf = {0, 0, 0, 0, 0, 0, 0, 0};
                    if (k0 < 600) {
                        af = *(const short8v*)(ha + k0);
                        bf = *(const short8v*)(wb + k0);
                    }
                    acc = __builtin_amdgcn_mfma_f32_16x16x32_bf16(af, bf, acc, 0, 0, 0);
                }
                const int brow = rt * 16 + (lane & 15);
                const int ch0  = ct * 16 + ((lane >> 4) << 2);
                *(f32x4*)(glds + brow * 68 + ch0) = acc;
            }
            __syncthreads();

            // gate epilogue: compute unconditionally, guard stores with ep
            {
                float gi = glds[(0 * 8 + eu) * 68 + s_loc] + xv0;
                float gf = glds[(1 * 8 + eu) * 68 + s_loc] + xv1;
                float gg = glds[(2 * 8 + eu) * 68 + s_loc] + xv2;
                float go = glds[(3 * 8 + eu) * 68 + s_loc] + xv3;
                float co = clds[ch * 8 + eu];
                float cn = sigm(gf) * co + sigm(gi) * tanh_f(gg);
                float hn = sigm(go) * tanh_f(cn);
                if (ep) clds[ch * 8 + eu] = cn;
                unsigned int pk = (unsigned int)f2bf(hn);
                unsigned int hi = __shfl_down(pk, 1, 64);
                if (ep && (eu & 1) == 0)
                    stu_agent((unsigned int*)Hw + (size_t)ch * 300 + ((u0 + eu) >> 1),
                              pk | (hi << 16));
                if (ep && k == L - 1)
                    EMB[(size_t)ch * 600 + u0 + eu] = hn;
            }
        }
        if (k < lmax - 1) barrier4<15, 5>(sync, wg, k);   // 75 = 15 buckets x 5
    }
}

// ---------------- stage-2 LSTM: 256 wgs x 8 units; 512 thr (r7-proven, 955us) ----------------
__global__ void __launch_bounds__(512) k_s2(
    const float* __restrict__ X2, const float* __restrict__ Whh2,
    float* __restrict__ h2, float* __restrict__ PH, int* __restrict__ sync)
{
    __shared__ float hl[NH2];
    const int wg   = blockIdx.x;
    const int tid  = threadIdx.x;
    const int lane = tid & 63;
    const int w    = tid >> 6;         // wave = unit 0..7
    const int uu   = wg * 8 + w;
    int* syncg = sync + 2048;          // s2 region

    // preload 4 gate rows fp32 into VGPRs: wv[g][j*4+c] = Whh2[g*2048+uu][j*256+lane*4+c]
    float wv[4][32];
#pragma unroll
    for (int g = 0; g < 4; ++g) {
        const float* rp = Whh2 + ((size_t)(g * NH2 + uu)) * NH2 + lane * 4;
#pragma unroll
        for (int j = 0; j < 8; ++j) {
            float4 a = *(const float4*)(rp + j * 256);
            wv[g][j * 4 + 0] = a.x; wv[g][j * 4 + 1] = a.y;
            wv[g][j * 4 + 2] = a.z; wv[g][j * 4 + 3] = a.w;
        }
    }
    *(float4*)(hl + tid * 4) = make_float4(0.f, 0.f, 0.f, 0.f);   // h(0) = 0
    float creg = 0.f;
    __syncthreads();

    for (int t = 0; t < PSEQ; ++t) {
        // prefetch x gate values (lane0 of each wave), independent of h
        float x0 = 0, x1 = 0, x2 = 0, x3 = 0;
        if (lane == 0) {
            const float* xr = X2 + (size_t)t * (4 * NH2) + uu;
            x0 = xr[0]; x1 = xr[NH2]; x2 = xr[2 * NH2]; x3 = xr[3 * NH2];
        }
        float a0 = 0, a1 = 0, a2 = 0, a3 = 0;
#pragma unroll
        for (int j = 0; j < 8; ++j) {
            float4 hv = *(const float4*)(hl + j * 256 + lane * 4);
            a0 = fmaf(wv[0][j*4+0], hv.x, a0); a0 = fmaf(wv[0][j*4+1], hv.y, a0);
            a0 = fmaf(wv[0][j*4+2], hv.z, a0); a0 = fmaf(wv[0][j*4+3], hv.w, a0);
            a1 = fmaf(wv[1][j*4+0], hv.x, a1); a1 = fmaf(wv[1][j*4+1], hv.y, a1);
            a1 = fmaf(wv[1][j*4+2], hv.z, a1); a1 = fmaf(wv[1][j*4+3], hv.w, a1);
            a2 = fmaf(wv[2][j*4+0], hv.x, a2); a2 = fmaf(wv[2][j*4+1], hv.y, a2);
            a2 = fmaf(wv[2][j*4+2], hv.z, a2); a2 = fmaf(wv[2][j*4+3], hv.w, a2);
            a3 = fmaf(wv[3][j*4+0], hv.x, a3); a3 = fmaf(wv[3][j*4+1], hv.y, a3);
            a3 = fmaf(wv[3][j*4+2], hv.z, a3); a3 = fmaf(wv[3][j*4+3], hv.w, a3);
        }
#pragma unroll
        for (int m = 32; m > 0; m >>= 1) {
            a0 += __shfl_xor(a0, m, 64); a1 += __shfl_xor(a1, m, 64);
            a2 += __shfl_xor(a2, m, 64); a3 += __shfl_xor(a3, m, 64);
        }
        if (lane == 0) {
            float gi = a0 + x0, gf = a1 + x1, gg = a2 + x2, go = a3 + x3;
            float cn = sigm(gf) * creg + sigm(gi) * tanh_f(gg);
            float hn = sigm(go) * tanh_f(cn);
            creg = cn;
            stf_agent(h2 + (size_t)((t + 1) & 1) * NH2 + uu, hn);
            PH[(size_t)t * NH2 + uu] = hn;
        }
        if (t < PSEQ - 1) {
            barrier3(syncg, wg, 16, 16, t);   // 256 = 16 x 16
            // stage next h: 4 coherent dword loads per thread -> LDS
            const float* hb = h2 + (size_t)((t + 1) & 1) * NH2 + tid * 4;
            float4 hv;
            hv.x = ldf_agent(hb + 0);
            hv.y = ldf_agent(hb + 1);
            hv.z = ldf_agent(hb + 2);
            hv.w = ldf_agent(hb + 3);
            *(float4*)(hl + tid * 4) = hv;
            __syncthreads();
        }
    }
}

// ---------------- column sum of S -> SSUM ----------------
__global__ void __launch_bounds__(256) k_colsum(const float* __restrict__ S, float* __restrict__ out)
{
    const int j = blockIdx.x * 256 + threadIdx.x;
    float a = 0.f;
    for (int t = 0; t < PSEQ; ++t) a += S[(size_t)t * NH2 + j];
    out[j] = a;
}

// ---------------- matvec: vout[r] = W[r]·vin + bscale*b[r] ----------------
__global__ void __launch_bounds__(256) k_mv(
    const float* __restrict__ W, const float* __restrict__ b, float bscale,
    const float* __restrict__ vin, float* __restrict__ vout)
{
    __shared__ float v[NH2];
    for (int i = threadIdx.x; i < NH2; i += 256) v[i] = vin[i];
    __syncthreads();
    const int r = blockIdx.x * 256 + threadIdx.x;
    const float4* wr = (const float4*)(W + (size_t)r * NH2);
    float a0 = 0, a1 = 0, a2 = 0, a3 = 0;
    for (int k4 = 0; k4 < NH2 / 4; ++k4) {
        float4 w4 = wr[k4];
        float4 x4 = *(const float4*)(&v[k4 * 4]);
        a0 = fmaf(w4.x, x4.x, a0); a1 = fmaf(w4.y, x4.y, a1);
        a2 = fmaf(w4.z, x4.z, a2); a3 = fmaf(w4.w, x4.w, a3);
    }
    vout[r] = (a0 + a1) + (a2 + a3) + bscale * b[r];
}

extern "C" void kernel_launch(void* const* d_in, const int* in_sizes, int n_in,
                              void* d_out, int out_size, void* d_ws, size_t ws_size,
                              hipStream_t stream)
{
    const float* sent   = (const float*)d_in[0];
    const float* action = (const float*)d_in[1];
    const int*   apos   = (const int*)  d_in[2];
    const float* Wih1   = (const float*)d_in[3];
    const float* Whh1   = (const float*)d_in[4];
    const float* bih1   = (const float*)d_in[5];
    const float* bhh1   = (const float*)d_in[6];
    const float* W1     = (const float*)d_in[7];
    const float* b1     = (const float*)d_in[8];
    const float* Wih2   = (const float*)d_in[9];
    const float* Whh2   = (const float*)d_in[10];
    const float* bih2   = (const float*)d_in[11];
    const float* bhh2   = (const float*)d_in[12];
    const float* W2     = (const float*)d_in[13];
    const float* b2     = (const float*)d_in[14];
    const float* ipw    = (const float*)d_in[15];
    const float* ipb    = (const float*)d_in[16];
    const float* opw    = (const float*)d_in[17];
    const float* opb    = (const float*)d_in[18];

    char* ws = (char*)d_ws;
    float*     X1   = (float*)(ws + OFF_X1);
    uint64_t*  HBUF = (uint64_t*)(ws + OFF_HBF);
    float*     EMB  = (float*)(ws + OFF_EMB);
    float*     EMB2 = (float*)(ws + OFF_EMB2);
    float*     X2   = (float*)(ws + OFF_X2);
    float*     PH   = (float*)(ws + OFF_PH);
    float*     S    = (float*)(ws + OFF_S);
    float*     H2   = (float*)(ws + OFF_H2);
    float*     SSUM = (float*)(ws + OFF_SSUM);
    float*     TMP  = (float*)(ws + OFF_TMP);
    int*       META = (int*)  (ws + OFF_META);
    int*       SYNC = (int*)  (ws + OFF_SYNC);

    // re-zero h(0) buffers + barrier counters every call (graph replays)
    hipMemsetAsync(ws + OFF_HBF, 0, SZ_HBF, stream);
    hipMemsetAsync(ws + OFF_H2, 0, SZ_H2, stream);
    hipMemsetAsync(ws + OFF_SYNC, 0, SZ_SYNC, stream);

    hipFuncSetAttribute((const void*)k_s1, hipFuncAttributeMaxDynamicSharedMemorySize, S1_LDS);
    hipFuncSetAttribute((const void*)gemm_mfma, hipFuncAttributeMaxDynamicSharedMemorySize, GM_LDS);

    // segment starts / lengths / sort (LDS-scanned)
    k_start<<<1, 256, 0, stream>>>(action, apos, META);
    // X1 = sent @ Wih1.T + bih1 + bhh1   (2048 x 2400, K=300)
    gemm_mfma<<<dim3(16, 19), 512, GM_LDS, stream>>>(sent, TSEQ, DIN, Wih1, 4 * NH1, bih1, bhh1, X1, 0);
    // stage-1 chains (MFMA, r10 form) -> EMB
    k_s1<<<75, 512, S1_LDS, stream>>>(X1, Whh1, META, HBUF, EMB, SYNC);
    // EMB2 = tanh(EMB @ W1.T + b1)       (256 x 600, K=600)
    gemm_mfma<<<dim3(2, 5), 512, GM_LDS, stream>>>(EMB, PSEQ, NH1, W1, NH1, b1, nullptr, EMB2, 1);
    // X2 = EMB2 @ Wih2.T + bih2 + bhh2   (256 x 8192, K=600)
    gemm_mfma<<<dim3(2, 64), 512, GM_LDS, stream>>>(EMB2, PSEQ, NH1, Wih2, 4 * NH2, bih2, bhh2, X2, 0);
    // stage-2 LSTM (256 wgs, barrier3 — r7-proven) -> PH (256 x 2048)
    k_s2<<<256, 512, 0, stream>>>(X2, Whh2, H2, PH, SYNC);
    // S = tanh(PH @ W2.T + b2)           (256 x 2048, K=2048)
    gemm_mfma<<<dim3(2, 16), 512, GM_LDS, stream>>>(PH, PSEQ, NH2, W2, NH2, b2, nullptr, S, 1);
    // SSUM = column sums of S
    k_colsum<<<8, 256, 0, stream>>>(S, SSUM);
    // attention collapse: out = (SSUM @ Wv.T + 256*bv) @ Wo.T + 256*bo
    k_mv<<<8, 256, 0, stream>>>(ipw + (size_t)4096 * NH2, ipb + 4096, 256.f, SSUM, TMP);
    k_mv<<<8, 256, 0, stream>>>(opw, opb, 256.f, TMP, (float*)d_out);
}